// Round 1
// baseline (231.237 us; speedup 1.0000x reference)
//
#include <hip/hip_runtime.h>
#include <hip/hip_bf16.h>

typedef __attribute__((ext_vector_type(8))) short bf16x8;
typedef __attribute__((ext_vector_type(4))) float f32x4;

#define SEQ  2048
#define NH   16
#define DH   64

__device__ __forceinline__ unsigned short f2bf(float f) {
  union { float f; unsigned int u; } v; v.f = f;
  unsigned int r = v.u + 0x7FFFu + ((v.u >> 16) & 1u);
  return (unsigned short)(r >> 16);
}

__device__ __forceinline__ void load_lds16(const void* g, void* l) {
  __builtin_amdgcn_global_load_lds(
      (const __attribute__((address_space(1))) unsigned int*)g,
      (__attribute__((address_space(3))) unsigned int*)l, 16, 0, 0);
}

// ---------------- LayerNorm + cast to bf16 ----------------
__global__ __launch_bounds__(256) void ln_cast_kernel(
    const float* __restrict__ x, const float* __restrict__ gg,
    const float* __restrict__ bb, unsigned short* __restrict__ xn) {
  int row = blockIdx.x;                     // 0..4095
  int t = threadIdx.x;                      // 0..255, 4 floats each
  const float* xr = x + (size_t)row * 1024;
  float4 v = ((const float4*)xr)[t];
  float s  = v.x + v.y + v.z + v.w;
  float ss = v.x*v.x + v.y*v.y + v.z*v.z + v.w*v.w;
  #pragma unroll
  for (int m = 1; m < 64; m <<= 1) {
    s  += __shfl_xor(s, m);
    ss += __shfl_xor(ss, m);
  }
  __shared__ float red[8];
  int wave = t >> 6;
  if ((t & 63) == 0) { red[wave] = s; red[wave + 4] = ss; }
  __syncthreads();
  s  = red[0] + red[1] + red[2] + red[3];
  ss = red[4] + red[5] + red[6] + red[7];
  float mu  = s * (1.0f / 1024.0f);
  float var = ss * (1.0f / 1024.0f) - mu * mu;
  float rstd = rsqrtf(var + 1e-5f);
  float4 g4 = ((const float4*)gg)[t];
  float4 b4 = ((const float4*)bb)[t];
  ushort4 o;
  o.x = f2bf((v.x - mu) * rstd * g4.x + b4.x);
  o.y = f2bf((v.y - mu) * rstd * g4.y + b4.y);
  o.z = f2bf((v.z - mu) * rstd * g4.z + b4.z);
  o.w = f2bf((v.w - mu) * rstd * g4.w + b4.w);
  ((ushort4*)(xn + (size_t)row * 1024))[t] = o;
}

// ---------------- transpose + cast: w[K][Nn] fp32 -> wt[Nn][K] bf16 ----------------
__global__ __launch_bounds__(256) void transpose_cast_kernel(
    const float* __restrict__ w, unsigned short* __restrict__ wt,
    int K, int Nn) {
  __shared__ unsigned short tile[64][68];
  int k0 = blockIdx.y * 64;
  int n0 = blockIdx.x * 64;
  int t = threadIdx.x;
  int tr = t >> 4;            // 0..15
  int tc = (t & 15) * 4;      // 0..60
  #pragma unroll
  for (int it = 0; it < 4; ++it) {
    int r = tr + it * 16;
    float4 v = *(const float4*)(w + (size_t)(k0 + r) * Nn + n0 + tc);
    tile[r][tc + 0] = f2bf(v.x);
    tile[r][tc + 1] = f2bf(v.y);
    tile[r][tc + 2] = f2bf(v.z);
    tile[r][tc + 3] = f2bf(v.w);
  }
  __syncthreads();
  #pragma unroll
  for (int it = 0; it < 4; ++it) {
    int nr = tr + it * 16;
    ushort4 o;
    o.x = tile[tc + 0][nr];
    o.y = tile[tc + 1][nr];
    o.z = tile[tc + 2][nr];
    o.w = tile[tc + 3][nr];
    *(ushort4*)(wt + (size_t)(n0 + nr) * K + k0 + tc) = o;
  }
}

// ---------------- GEMM: C[M][Nn] = A[M][1024] * Bt[Nn][1024]^T + bias ----------------
// MODE 0: QKV epilogue (scatter to q/k/v [B,H,N,64], q scaled by 0.125)
// MODE 1: fp32 out [M][1024] + bias
template<int MODE>
__global__ __launch_bounds__(256) void gemm_kernel(
    const unsigned short* __restrict__ A,
    const unsigned short* __restrict__ Bt,
    const float* __restrict__ bias,
    float* __restrict__ outF,
    unsigned short* __restrict__ qw,
    unsigned short* __restrict__ kw,
    unsigned short* __restrict__ vw)
{
  constexpr int K = 1024;
  __shared__ __align__(16) unsigned short As[128 * 32];
  __shared__ __align__(16) unsigned short Bs[128 * 32];
  int tid = threadIdx.x;
  int wave = tid >> 6, lane = tid & 63;
  int col = lane & 15, g = lane >> 4;
  int m0 = blockIdx.y * 128, n0 = blockIdx.x * 128;
  int wm = (wave >> 1) * 64, wn = (wave & 1) * 64;
  int r0 = tid >> 2, ch = (tid & 3) * 8;

  f32x4 acc[4][4] = {};

  const unsigned short* ga = A  + (size_t)(m0 + r0) * K + ch;
  const unsigned short* gb = Bt + (size_t)(n0 + r0) * K + ch;
  unsigned short* lA0 = &As[wave * 512];
  unsigned short* lA1 = &As[2048 + wave * 512];
  unsigned short* lB0 = &Bs[wave * 512];
  unsigned short* lB1 = &Bs[2048 + wave * 512];

  for (int kt = 0; kt < K; kt += 32) {
    __syncthreads();
    load_lds16(ga + kt,                  lA0);
    load_lds16(ga + (size_t)64 * K + kt, lA1);
    load_lds16(gb + kt,                  lB0);
    load_lds16(gb + (size_t)64 * K + kt, lB1);
    __syncthreads();
    bf16x8 af[4], bfr[4];
    #pragma unroll
    for (int i = 0; i < 4; ++i)
      af[i] = *(const bf16x8*)&As[(wm + i * 16 + col) * 32 + g * 8];
    #pragma unroll
    for (int i = 0; i < 4; ++i)
      bfr[i] = *(const bf16x8*)&Bs[(wn + i * 16 + col) * 32 + g * 8];
    #pragma unroll
    for (int mi = 0; mi < 4; ++mi)
      #pragma unroll
      for (int ni = 0; ni < 4; ++ni)
        acc[mi][ni] = __builtin_amdgcn_mfma_f32_16x16x32_bf16(
            af[mi], bfr[ni], acc[mi][ni], 0, 0, 0);
  }

  if (MODE == 0) {
    #pragma unroll
    for (int ni = 0; ni < 4; ++ni) {
      int n = n0 + wn + ni * 16 + col;
      float bv = bias[n];
      int t3 = n >> 10;
      int within = n & 1023;
      int h = within >> 6, d = within & 63;
      unsigned short* dst = (t3 == 0) ? qw : (t3 == 1) ? kw : vw;
      float scl = (t3 == 0) ? 0.125f : 1.0f;
      #pragma unroll
      for (int mi = 0; mi < 4; ++mi) {
        int mb = m0 + wm + mi * 16 + g * 4;
        #pragma unroll
        for (int j = 0; j < 4; ++j) {
          int m = mb + j;
          int b = m >> 11, tok = m & 2047;
          float val = (acc[mi][ni][j] + bv) * scl;
          dst[(((size_t)(b * NH + h) * SEQ + tok) << 6) + d] = f2bf(val);
        }
      }
    }
  } else {
    #pragma unroll
    for (int ni = 0; ni < 4; ++ni) {
      int n = n0 + wn + ni * 16 + col;
      float bv = bias[n];
      #pragma unroll
      for (int mi = 0; mi < 4; ++mi) {
        int mb = m0 + wm + mi * 16 + g * 4;
        #pragma unroll
        for (int j = 0; j < 4; ++j)
          outF[(size_t)(mb + j) * 1024 + n] = acc[mi][ni][j] + bv;
      }
    }
  }
}

// ---------------- flash attention ----------------
// grid: x = SEQ/64 q-tiles, y = B*H. 4 waves/block, 16 q-rows per wave.
__global__ __launch_bounds__(256) void attn_kernel(
    const unsigned short* __restrict__ qg,   // [B*H][SEQ][64], pre-scaled
    const unsigned short* __restrict__ kg,
    const unsigned short* __restrict__ vg,
    unsigned short* __restrict__ og)         // [B][SEQ][1024] bf16
{
  __shared__ __align__(16) unsigned short VT[64][72];
  __shared__ __align__(16) unsigned short P[4][16][72];
  int tid = threadIdx.x;
  int wave = tid >> 6, lane = tid & 63;
  int col = lane & 15, g = lane >> 4;
  int bh = blockIdx.y;
  int b = bh >> 4, h = bh & 15;
  int q0 = blockIdx.x * 64;
  const unsigned short* Q = qg + (size_t)bh * SEQ * DH;
  const unsigned short* Kp = kg + (size_t)bh * SEQ * DH;
  const unsigned short* V = vg + (size_t)bh * SEQ * DH;

  int qrow0 = q0 + wave * 16;
  bf16x8 qf0 = *(const bf16x8*)&Q[(qrow0 + col) * DH + g * 8];
  bf16x8 qf1 = *(const bf16x8*)&Q[(qrow0 + col) * DH + 32 + g * 8];

  f32x4 oacc[4] = {};
  float mrow[4], lrow[4];
  #pragma unroll
  for (int j = 0; j < 4; ++j) { mrow[j] = -1e30f; lrow[j] = 0.0f; }

  int vkey = tid >> 2;
  int vdc = (tid & 3) * 16;

  for (int kt = 0; kt < SEQ; kt += 64) {
    __syncthreads();
    // stage V^T tile (coalesced global read, scalar LDS scatter)
    bf16x8 v0 = *(const bf16x8*)&V[(size_t)(kt + vkey) * DH + vdc];
    bf16x8 v1 = *(const bf16x8*)&V[(size_t)(kt + vkey) * DH + vdc + 8];
    #pragma unroll
    for (int jj = 0; jj < 8; ++jj) VT[vdc + jj][vkey] = (unsigned short)v0[jj];
    #pragma unroll
    for (int jj = 0; jj < 8; ++jj) VT[vdc + 8 + jj][vkey] = (unsigned short)v1[jj];

    // S = Q K^T  (K frags straight from global; L1/L2-resident)
    f32x4 s[4];
    #pragma unroll
    for (int ns = 0; ns < 4; ++ns) {
      s[ns] = (f32x4){0.f, 0.f, 0.f, 0.f};
      bf16x8 kf0 = *(const bf16x8*)&Kp[(size_t)(kt + ns * 16 + col) * DH + g * 8];
      bf16x8 kf1 = *(const bf16x8*)&Kp[(size_t)(kt + ns * 16 + col) * DH + 32 + g * 8];
      s[ns] = __builtin_amdgcn_mfma_f32_16x16x32_bf16(qf0, kf0, s[ns], 0, 0, 0);
      s[ns] = __builtin_amdgcn_mfma_f32_16x16x32_bf16(qf1, kf1, s[ns], 0, 0, 0);
    }

    // online softmax; rows g*4+j live across the 16 lanes of this lane-group
    float tmax[4];
    #pragma unroll
    for (int j = 0; j < 4; ++j)
      tmax[j] = fmaxf(fmaxf(s[0][j], s[1][j]), fmaxf(s[2][j], s[3][j]));
    #pragma unroll
    for (int m = 1; m <= 8; m <<= 1)
      #pragma unroll
      for (int j = 0; j < 4; ++j) tmax[j] = fmaxf(tmax[j], __shfl_xor(tmax[j], m));

    float corr[4], rsum[4];
    #pragma unroll
    for (int j = 0; j < 4; ++j) {
      float mn = fmaxf(mrow[j], tmax[j]);
      corr[j] = __expf(mrow[j] - mn);
      mrow[j] = mn;
      rsum[j] = 0.f;
    }
    #pragma unroll
    for (int ns = 0; ns < 4; ++ns)
      #pragma unroll
      for (int j = 0; j < 4; ++j) {
        float p = __expf(s[ns][j] - mrow[j]);
        s[ns][j] = p;
        rsum[j] += p;
      }
    #pragma unroll
    for (int m = 1; m <= 8; m <<= 1)
      #pragma unroll
      for (int j = 0; j < 4; ++j) rsum[j] += __shfl_xor(rsum[j], m);
    #pragma unroll
    for (int j = 0; j < 4; ++j) lrow[j] = lrow[j] * corr[j] + rsum[j];
    #pragma unroll
    for (int ds = 0; ds < 4; ++ds)
      #pragma unroll
      for (int j = 0; j < 4; ++j) oacc[ds][j] *= corr[j];

    // P -> LDS (per-wave buffer, bf16)
    #pragma unroll
    for (int ns = 0; ns < 4; ++ns)
      #pragma unroll
      for (int j = 0; j < 4; ++j)
        P[wave][g * 4 + j][ns * 16 + col] = f2bf(s[ns][j]);

    __syncthreads();   // VT staged + visible

    // O += P * V  (A-frags from P, B-frags from VT, both ds_read_b128)
    #pragma unroll
    for (int ds = 0; ds < 4; ++ds)
      #pragma unroll
      for (int c = 0; c < 2; ++c) {
        bf16x8 pf = *(const bf16x8*)&P[wave][col][c * 32 + g * 8];
        bf16x8 vf = *(const bf16x8*)&VT[ds * 16 + col][c * 32 + g * 8];
        oacc[ds] = __builtin_amdgcn_mfma_f32_16x16x32_bf16(pf, vf, oacc[ds], 0, 0, 0);
      }
  }

  float inv[4];
  #pragma unroll
  for (int j = 0; j < 4; ++j) inv[j] = 1.0f / lrow[j];
  unsigned short* orow = og + (size_t)b * SEQ * 1024 + h * DH;
  #pragma unroll
  for (int ds = 0; ds < 4; ++ds)
    #pragma unroll
    for (int j = 0; j < 4; ++j)
      orow[(size_t)(qrow0 + g * 4 + j) * 1024 + ds * 16 + col] =
          f2bf(oacc[ds][j] * inv[j]);
}

extern "C" void kernel_launch(void* const* d_in, const int* in_sizes, int n_in,
                              void* d_out, int out_size, void* d_ws, size_t ws_size,
                              hipStream_t stream) {
  const float* x      = (const float*)d_in[0];
  const float* ln_g   = (const float*)d_in[1];
  const float* ln_b   = (const float*)d_in[2];
  const float* w_qkv  = (const float*)d_in[3];
  const float* b_qkv  = (const float*)d_in[4];
  const float* w_proj = (const float*)d_in[5];
  const float* b_proj = (const float*)d_in[6];
  float* out = (float*)d_out;

  unsigned short* ws = (unsigned short*)d_ws;
  unsigned short* xn     = ws;                       // 4096*1024
  unsigned short* wqkvT  = ws + 4194304;             // 3072*1024
  unsigned short* wprojT = wqkvT + 3145728;          // 1024*1024
  unsigned short* qw     = wprojT + 1048576;         // 32*2048*64
  unsigned short* kw     = qw + 4194304;
  unsigned short* vw     = kw + 4194304;
  unsigned short* ao     = xn;                       // reuse xn after QKV GEMM

  ln_cast_kernel<<<dim3(4096), dim3(256), 0, stream>>>(x, ln_g, ln_b, xn);
  transpose_cast_kernel<<<dim3(48, 16), dim3(256), 0, stream>>>(w_qkv, wqkvT, 1024, 3072);
  transpose_cast_kernel<<<dim3(16, 16), dim3(256), 0, stream>>>(w_proj, wprojT, 1024, 1024);
  gemm_kernel<0><<<dim3(24, 32), dim3(256), 0, stream>>>(
      xn, wqkvT, b_qkv, nullptr, qw, kw, vw);
  attn_kernel<<<dim3(32, 32), dim3(256), 0, stream>>>(qw, kw, vw, ao);
  gemm_kernel<1><<<dim3(8, 32), dim3(256), 0, stream>>>(
      ao, wprojT, b_proj, out, nullptr, nullptr, nullptr);
}